// Round 13
// baseline (115.543 us; speedup 1.0000x reference)
//
#include <hip/hip_runtime.h>
#include <hip/hip_bf16.h>

#define NT 4096      // H*W
#define CF 256       // feature channels
// CQK = 64

typedef __attribute__((ext_vector_type(8))) short bf16x8;
typedef __attribute__((ext_vector_type(4))) float f32x4;
typedef __attribute__((ext_vector_type(4))) short s16x4;

__device__ __forceinline__ short f2bf(float f) {
  union { float f; unsigned u; } v; v.f = f;
  unsigned r = v.u + 0x7FFFu + ((v.u >> 16) & 1u);   // RTNE
  return (short)(r >> 16);
}
__device__ __forceinline__ float bf2f(short s) {
  union { unsigned u; float f; } w; w.u = ((unsigned)(unsigned short)s) << 16;
  return w.f;
}

// async global->LDS, 16B per lane; LDS dest = wave-uniform base + lane*16
__device__ __forceinline__ void glds16(const void* g, void* l) {
  __builtin_amdgcn_global_load_lds(
      (const __attribute__((address_space(1))) void*)g,
      (__attribute__((address_space(3))) void*)l, 16, 0, 0);
}

// bare hardware exp2 (log2-domain scores shifted to <= ~0; finite args)
__device__ __forceinline__ float fexp2(float x) {
  float r;
  asm("v_exp_f32 %0, %1" : "=v"(r) : "v"(x));
  return r;
}

// ---------------------------------------------------------------------------
// Q projection + per-row squared norm (for the static softmax bound).
// ---------------------------------------------------------------------------
__global__ __launch_bounds__(256, 2)
void proj_src_kernel(const float* __restrict__ X, const float* __restrict__ W,
                     const float* __restrict__ Bv, short* __restrict__ Y,
                     float scale, float* __restrict__ qnorm2)
{
  __shared__ alignas(16) short Xlds[64 * 256];   // 32KB; reused as norm scratch
  const int tid = threadIdx.x;
  const int wv = tid >> 6, l = tid & 63;
  const int l15 = l & 15, l4 = l >> 4;
  const int i0 = blockIdx.x * 64;
  const int b  = blockIdx.y;
  const float* Xb = X + (size_t)b * CF * NT;

#pragma unroll
  for (int it = 0; it < 16; ++it) {
    int c0 = it * 16 + wv * 4;
    float x0 = Xb[(size_t)(c0 + 0) * NT + i0 + l];
    float x1 = Xb[(size_t)(c0 + 1) * NT + i0 + l];
    float x2 = Xb[(size_t)(c0 + 2) * NT + i0 + l];
    float x3 = Xb[(size_t)(c0 + 3) * NT + i0 + l];
    s16x4 pk; pk[0] = f2bf(x0); pk[1] = f2bf(x1); pk[2] = f2bf(x2); pk[3] = f2bf(x3);
    int phys = (l * 512 + c0 * 2) ^ ((l & 31) << 4);
    *(s16x4*)((char*)Xlds + phys) = pk;
  }
  __syncthreads();

  f32x4 acc[4] = {};
  const int o = wv * 16 + l15;

#pragma unroll
  for (int kk = 0; kk < 8; ++kk) {
    bf16x8 a[4];
#pragma unroll
    for (int mi = 0; mi < 4; ++mi) {
      int i = 16 * mi + l15;
      int phys = (i * 512 + kk * 64 + l4 * 16) ^ ((i & 31) << 4);
      a[mi] = *(const bf16x8*)((const char*)Xlds + phys);
    }
    const float* wp = W + (size_t)o * CF + kk * 32 + l4 * 8;
    bf16x8 wf;
#pragma unroll
    for (int t = 0; t < 8; ++t) wf[t] = f2bf(wp[t]);
#pragma unroll
    for (int mi = 0; mi < 4; ++mi)
      acc[mi] = __builtin_amdgcn_mfma_f32_16x16x32_bf16(a[mi], wf, acc[mi], 0, 0, 0);
  }

  __syncthreads();                         // all waves done reading Xlds
  float* nlds = (float*)(void*)Xlds;       // [64][65] padded sq matrix
  const float bv = Bv[o];
#pragma unroll
  for (int mi = 0; mi < 4; ++mi)
#pragma unroll
    for (int r = 0; r < 4; ++r) {
      float val = (acc[mi][r] + bv) * scale;
      short sv = f2bf(val);
      int row = 16 * mi + l4 * 4 + r;
      Y[((size_t)b * NT + i0 + row) * 64 + o] = sv;
      float qr = bf2f(sv);
      nlds[row * 65 + o] = qr * qr;
    }
  __syncthreads();
  if (tid < 64) {
    float ss = 0.f;
#pragma unroll 8
    for (int j = 0; j < 64; ++j) ss += nlds[tid * 65 + j];
    qnorm2[(size_t)b * NT + i0 + tid] = ss;
  }
}

// ---------------------------------------------------------------------------
// Fused ref projections: K (B,NT,64) and Vt (B,256,NT) from ONE staging of
// ref, plus kmax2[b] = max_row |k_row|^2 (one atomicMax per wg).
// ---------------------------------------------------------------------------
__global__ __launch_bounds__(256, 2)
void proj_ref_kernel(const float* __restrict__ X,
                     const float* __restrict__ Wk, const float* __restrict__ Bk,
                     const float* __restrict__ Wv, const float* __restrict__ Bvv,
                     short* __restrict__ K, short* __restrict__ Vt,
                     unsigned* __restrict__ kmax2)
{
  __shared__ alignas(16) short Xlds[64 * 256];
  const int tid = threadIdx.x;
  const int wv = tid >> 6, l = tid & 63;
  const int l15 = l & 15, l4 = l >> 4;
  const int i0 = blockIdx.x * 64;
  const int b  = blockIdx.y;
  const float* Xb = X + (size_t)b * CF * NT;

#pragma unroll
  for (int it = 0; it < 16; ++it) {
    int c0 = it * 16 + wv * 4;
    float x0 = Xb[(size_t)(c0 + 0) * NT + i0 + l];
    float x1 = Xb[(size_t)(c0 + 1) * NT + i0 + l];
    float x2 = Xb[(size_t)(c0 + 2) * NT + i0 + l];
    float x3 = Xb[(size_t)(c0 + 3) * NT + i0 + l];
    s16x4 pk; pk[0] = f2bf(x0); pk[1] = f2bf(x1); pk[2] = f2bf(x2); pk[3] = f2bf(x3);
    int phys = (l * 512 + c0 * 2) ^ ((l & 31) << 4);
    *(s16x4*)((char*)Xlds + phys) = pk;
  }
  __syncthreads();

  f32x4 accK[4] = {};
  f32x4 accV[4][4] = {};
  const int oK = wv * 16 + l15;

#pragma unroll
  for (int kk = 0; kk < 8; ++kk) {
    bf16x8 a[4];
#pragma unroll
    for (int mi = 0; mi < 4; ++mi) {
      int i = 16 * mi + l15;
      int phys = (i * 512 + kk * 64 + l4 * 16) ^ ((i & 31) << 4);
      a[mi] = *(const bf16x8*)((const char*)Xlds + phys);
    }
    {
      const float* wp = Wk + (size_t)oK * CF + kk * 32 + l4 * 8;
      bf16x8 wf;
#pragma unroll
      for (int t = 0; t < 8; ++t) wf[t] = f2bf(wp[t]);
#pragma unroll
      for (int mi = 0; mi < 4; ++mi)
        accK[mi] = __builtin_amdgcn_mfma_f32_16x16x32_bf16(a[mi], wf, accK[mi], 0, 0, 0);
    }
#pragma unroll
    for (int no = 0; no < 4; ++no) {
      int oV = wv * 64 + 16 * no + l15;
      const float* wp = Wv + (size_t)oV * CF + kk * 32 + l4 * 8;
      bf16x8 wf;
#pragma unroll
      for (int t = 0; t < 8; ++t) wf[t] = f2bf(wp[t]);
#pragma unroll
      for (int mi = 0; mi < 4; ++mi)
        accV[mi][no] = __builtin_amdgcn_mfma_f32_16x16x32_bf16(a[mi], wf, accV[mi][no], 0, 0, 0);
    }
  }

#pragma unroll
  for (int no = 0; no < 4; ++no) {
    int oV = wv * 64 + 16 * no + l15;
    float bv = Bvv[oV];
#pragma unroll
    for (int mi = 0; mi < 4; ++mi) {
      s16x4 pk;
#pragma unroll
      for (int r = 0; r < 4; ++r) pk[r] = f2bf(accV[mi][no][r] + bv);
      *(s16x4*)&Vt[((size_t)b * CF + oV) * NT + i0 + 16 * mi + l4 * 4] = pk;
    }
  }

  __syncthreads();                         // all waves done reading Xlds
  float* nlds = (float*)(void*)Xlds;       // [64][65]
  const float bk = Bk[oK];
#pragma unroll
  for (int mi = 0; mi < 4; ++mi)
#pragma unroll
    for (int r = 0; r < 4; ++r) {
      float val = accK[mi][r] + bk;
      short sv = f2bf(val);
      int row = 16 * mi + l4 * 4 + r;
      K[((size_t)b * NT + i0 + row) * 64 + oK] = sv;
      float qr = bf2f(sv);
      nlds[row * 65 + oK] = qr * qr;
    }
  __syncthreads();
  if (tid < 64) {
    float ss = 0.f;
#pragma unroll 8
    for (int j = 0; j < 64; ++j) ss += nlds[tid * 65 + j];
#pragma unroll
    for (int m = 1; m <= 32; m <<= 1) ss = fmaxf(ss, __shfl_xor(ss, m, 64));
    if (tid == 0) atomicMax(&kmax2[b], __float_as_uint(ss));
  }
}

// ---------------------------------------------------------------------------
// Flash attention + residual.  LDS-staged K/V (global_load_lds, dbuf).
// wg = 4 waves (256 thr) = 128 q-rows x 128 cols; wave = 32 q-rows x 128 cols
// (G=2 row-groups of 16 sharing every K/V fragment read -> HALF the LDS read
// traffic of R12's 16-row waves; QK/PV/exp totals unchanged).
// Grid = 32 qt x 2 z x 4 b = 256 wgs = 1 wg/CU (1 wave/SIMD -- deliberate:
// LDS-BW bound, per-wave ILP covers read latency).
// STATIC softmax shift (Cauchy-Schwarz) folded into QK C-init.
// Arena 48KB: K dbuf 2x8KB at 0; V dbuf 2x16KB at 16384; epilogue reuse.
// ---------------------------------------------------------------------------
__global__ __launch_bounds__(256, 1)
void flash_kernel(const short* __restrict__ Q, const short* __restrict__ K,
                  const short* __restrict__ Vt, const float* __restrict__ src,
                  const float* __restrict__ gamma_p,
                  const float* __restrict__ qnorm2, const unsigned* __restrict__ kmax2,
                  float* __restrict__ out)
{
  __shared__ alignas(16) char arena[49152];

  const int tid = threadIdx.x;
  const int wv = tid >> 6, l = tid & 63;     // wv = 0..3
  const int l15 = l & 15, l4 = l >> 4;

  // id -> (b, qt, z); batch pinned to an XCD pair for L2 locality
  const int id = blockIdx.x;                 // 0..255
  const int x8 = id & 7;
  const int b  = x8 >> 1;
  const int widx = ((id >> 3) << 1) | (x8 & 1);   // 0..63
  const int qt = widx >> 1, z = widx & 1;
  const int i0 = qt * 128;
  const int cbase = z * 128;
  const int rowbase = i0 + wv * 32;               // wave's 32 query rows

  const short* Qb = Q + (size_t)b * NT * 64;
  const char*  Kb = (const char*)(K  + (size_t)b * NT * 64);
  const char*  Vb = (const char*)(Vt + (size_t)b * CF * NT);

  // Q fragments: 2 groups of 16 rows (B-operand: col=l15, k=l4*8..)
  bf16x8 qf[2][2];
#pragma unroll
  for (int g = 0; g < 2; ++g)
#pragma unroll
    for (int kk = 0; kk < 2; ++kk)
      qf[g][kk] = *(const bf16x8*)&Qb[(size_t)(rowbase + 16 * g + l15) * 64 + kk * 32 + l4 * 8];

  // static shift: C-init for QK = -M_i = -sqrt(qnorm2_i * kmax2)
  const float km2 = __uint_as_float(kmax2[b]);
  f32x4 c0[2];
#pragma unroll
  for (int g = 0; g < 2; ++g) {
    float mneg = -sqrtf(qnorm2[(size_t)b * NT + rowbase + 16 * g + l15] * km2);
    c0[g][0] = mneg; c0[g][1] = mneg; c0[g][2] = mneg; c0[g][3] = mneg;
  }

  const int a32 = ((l ^ 32) << 2);                // bpermute byte index (epilogue)

  // reader per-lane byte offsets (loop-invariant)
  const int kperm = 8 * (l15 >> 2) + (l15 & 3);
  const int swzk = (l15 & 3) | (((l15 >> 2) & 1) << 2);
  const int swzv = (l15 & 3) | (((l15 >> 3) & 1) << 2);
  int baseK[2], baseV[2];
#pragma unroll
  for (int kk = 0; kk < 2; ++kk) {
    baseK[kk] = kperm * 128 + (((kk * 4 + l4) ^ swzk) << 4);
    baseV[kk] = l15 * 128 + (((kk * 4 + l4) ^ swzv) << 4);
  }

  // staging: 24 1KB chunks/tile (K 8, V 16), 6 per wave; linear LDS dest +
  // inverse-swizzled global source (swz = (row&3) | ((row>>3&1)<<2))
  const char* sptr[6]; int sinc[6], doff0[6], dadd[6];
#pragma unroll
  for (int i = 0; i < 6; ++i) {
    int c = wv * 6 + i;
    if (c < 8) {              // K chunk: rows 8c..8c+7 (128B rows)
      int r = c * 8 + (l >> 3);
      int sw = (r & 3) | (((r >> 3) & 1) << 2);
      sptr[i] = Kb + r * 128 + (((l & 7) ^ sw) << 4);
      sinc[i] = 8192;         // next 64 keys
      doff0[i] = c * 1024;
      dadd[i] = 8192;
    } else {                  // V chunk: channels 8(c-8)..+7 of wg's 128
      int vr = (c - 8) * 8 + (l >> 3);
      int sw = (vr & 3) | (((vr >> 3) & 1) << 2);
      sptr[i] = Vb + (size_t)(cbase + vr) * (NT * 2) + (((l & 7) ^ sw) << 4);
      sinc[i] = 128;          // next 64 keys
      doff0[i] = 16384 + (c - 8) * 1024;
      dadd[i] = 16384;
    }
  }

  // prologue: stage tile 0 into parity 0
#pragma unroll
  for (int i = 0; i < 6; ++i) {
    glds16(sptr[i], arena + doff0[i]);
    sptr[i] += sinc[i];
  }
  __syncthreads();

  f32x4 acc[2][8] = {};
  float lrow[2] = { 0.f, 0.f };   // per-lane PARTIAL sums (own 16 key-slots)

  for (int jb = 0; jb < 64; ++jb) {
    const int cur = jb & 1;
    const char* Kc = arena + cur * 8192;
    const char* Vc = arena + 16384 + cur * 16384;

    // stage next tile (async; has the whole compute phase to land)
    if (jb < 63) {
      const int p = cur ^ 1;
#pragma unroll
      for (int i = 0; i < 6; ++i) {
        glds16(sptr[i], arena + doff0[i] + p * dadd[i]);
        sptr[i] += sinc[i];
      }
    }

    // K fragments (A-operand, permuted rows), shared by both q-groups
    bf16x8 kf[4][2];
#pragma unroll
    for (int nj = 0; nj < 4; ++nj) {
      const int ko = (nj >> 1) * 4096 + (nj & 1) * 512;
#pragma unroll
      for (int kk = 0; kk < 2; ++kk)
        kf[nj][kk] = *(const bf16x8*)(Kc + baseK[kk] + ko);
    }

    // S^T = K_perm @ Q^T - M  (static shift folded into C-init)
    f32x4 s[2][4];
    __builtin_amdgcn_s_setprio(1);
#pragma unroll
    for (int nj = 0; nj < 4; ++nj)
#pragma unroll
      for (int g = 0; g < 2; ++g) {
        s[g][nj] = __builtin_amdgcn_mfma_f32_16x16x32_bf16(kf[nj][0], qf[g][0], c0[g], 0, 0, 0);
        s[g][nj] = __builtin_amdgcn_mfma_f32_16x16x32_bf16(kf[nj][1], qf[g][1], s[g][nj], 0, 0, 0);
      }
    __builtin_amdgcn_s_setprio(0);

    // V fragments (B-operand): all 128 wg-cols, shared by both q-groups
    bf16x8 vb[8][2];
#pragma unroll
    for (int nv = 0; nv < 8; ++nv)
#pragma unroll
      for (int kk = 0; kk < 2; ++kk)
        vb[nv][kk] = *(const bf16x8*)(Vc + baseV[kk] + nv * 2048);

    // softmax numerators: p = 2^s (s <= ~0 by the static bound); no reduce,
    // no branch.  Per-lane partial sum accumulates into lrow.
    bf16x8 pa[2][2];
#pragma unroll
    for (int g = 0; g < 2; ++g) {
#pragma unroll
      for (int nj = 0; nj < 4; ++nj)
#pragma unroll
        for (int r = 0; r < 4; ++r)
          s[g][nj][r] = fexp2(s[g][nj][r]);

      lrow[g] += ((s[g][0][0] + s[g][0][1]) + (s[g][0][2] + s[g][0][3]))
               + ((s[g][1][0] + s[g][1][1]) + (s[g][1][2] + s[g][1][3]))
               + ((s[g][2][0] + s[g][2][1]) + (s[g][2][2] + s[g][2][3]))
               + ((s[g][3][0] + s[g][3][1]) + (s[g][3][2] + s[g][3][3]));

      unsigned pk[4][2];
#pragma unroll
      for (int nj = 0; nj < 4; ++nj)
#pragma unroll
        for (int h = 0; h < 2; ++h)
          asm("v_cvt_pk_bf16_f32 %0, %1, %2"
              : "=v"(pk[nj][h]) : "v"(s[g][nj][2 * h]), "v"(s[g][nj][2 * h + 1]));
#pragma unroll
      for (int kk = 0; kk < 2; ++kk) {
        union { unsigned u[4]; bf16x8 v; } u;
        u.u[0] = pk[2 * kk][0];     u.u[1] = pk[2 * kk][1];
        u.u[2] = pk[2 * kk + 1][0]; u.u[3] = pk[2 * kk + 1][1];
        pa[g][kk] = u.v;
      }
    }

    // O += P @ V  (V frags amortized over both q-groups)
    __builtin_amdgcn_s_setprio(1);
#pragma unroll
    for (int kk = 0; kk < 2; ++kk)
#pragma unroll
      for (int g = 0; g < 2; ++g)
#pragma unroll
        for (int nv = 0; nv < 8; ++nv)
          acc[g][nv] = __builtin_amdgcn_mfma_f32_16x16x32_bf16(pa[g][kk], vb[nv][kk], acc[g][nv], 0, 0, 0);
    __builtin_amdgcn_s_setprio(0);

    __syncthreads();   // implicit vmcnt(0): next-tile stage landed; reads done
  }

  // ---- epilogue: reduce row sums ONCE, normalize, transpose, residual ----
  float* Obuf = (float*)(void*)arena + wv * (16 * 132);
  const float gm = gamma_p[0];
  const float* srcb = src + (size_t)b * CF * NT;
  float* outb = out + (size_t)b * CF * NT;

#pragma unroll
  for (int g = 0; g < 2; ++g) {
    float lf = lrow[g];
    lf += __int_as_float(__builtin_amdgcn_ds_swizzle(__float_as_int(lf), 0x401F));
    lf += __int_as_float(__builtin_amdgcn_ds_bpermute(a32, __float_as_int(lf)));
    float li[4];
#pragma unroll
    for (int r = 0; r < 4; ++r)
      li[r] = 1.0f / __shfl(lf, 4 * l4 + r, 64);
#pragma unroll
    for (int nv = 0; nv < 8; ++nv)
#pragma unroll
      for (int r = 0; r < 4; ++r)
        Obuf[(4 * l4 + r) * 132 + 16 * nv + l15] = acc[g][nv][r] * li[r];
    // same-wave LDS write->read; per-wave disjoint regions, in-order DS
#pragma unroll 4
    for (int t = 0; t < 32; ++t) {
      int c = cbase + l4 + 4 * t;
      size_t off = (size_t)c * NT + rowbase + 16 * g + l15;
      float v = Obuf[l15 * 132 + l4 + 4 * t];
      outb[off] = gm * v + srcb[off];
    }
  }
}

// ---------------------------------------------------------------------------
extern "C" void kernel_launch(void* const* d_in, const int* in_sizes, int n_in,
                              void* d_out, int out_size, void* d_ws, size_t ws_size,
                              hipStream_t stream) {
  const float* src    = (const float*)d_in[0];
  const float* ref    = (const float*)d_in[1];
  const float* w_src  = (const float*)d_in[2];
  const float* b_src  = (const float*)d_in[3];
  const float* w_ref  = (const float*)d_in[4];
  const float* b_ref  = (const float*)d_in[5];
  const float* w_gate = (const float*)d_in[6];
  const float* b_gate = (const float*)d_in[7];
  const float* gamma  = (const float*)d_in[8];
  float* out = (float*)d_out;

  const size_t qk_elems = (size_t)4 * NT * 64;
  const size_t v_elems  = (size_t)4 * CF * NT;
  const size_t base_bytes = (qk_elems * 2 + v_elems) * sizeof(short);
  if (ws_size < base_bytes + 4 * NT * sizeof(float) + 4 * sizeof(unsigned)) return;
  short* Qw = (short*)d_ws;
  short* Kw = Qw + qk_elems;
  short* Vw = Kw + qk_elems;
  float* qnormp = (float*)(Vw + v_elems);
  unsigned* kmaxp = (unsigned*)(qnormp + 4 * NT);

  hipMemsetAsync(kmaxp, 0, 4 * sizeof(unsigned), stream);

  dim3 blk(256);
  dim3 gp(NT / 64, 4);
  // fold energy scale (1/16) AND log2(e) into Q so scores are log2-domain
  proj_src_kernel<<<gp, blk, 0, stream>>>(src, w_src, b_src, Qw,
                                          0.0625f * 1.44269504f, qnormp);
  proj_ref_kernel<<<gp, blk, 0, stream>>>(ref, w_ref, b_ref, w_gate, b_gate,
                                          Kw, Vw, kmaxp);

  flash_kernel<<<dim3(256), blk, 0, stream>>>(Qw, Kw, Vw, src, gamma, qnormp, kmaxp, out);
}